// Round 12
// baseline (51.927 us; speedup 1.0000x reference)
//
#include <hip/hip_runtime.h>

typedef unsigned short u16;
typedef __attribute__((ext_vector_type(8))) short bf16x8;  // 8 bf16 = 4 VGPRs (MFMA A/B frag)
typedef __attribute__((ext_vector_type(4))) float f32x4;   // MFMA C/D frag

constexpr int   kN    = 8192;
constexpr int   kD    = 256;
constexpr float kInvD = 1.0f / 256.0f;
constexpr float kInv2D = 2.0f / 256.0f;   // 2/D
constexpr float kInvN = 1.0f / 8192.0f;

#define GLOAD_LDS16(gptr, ldsptr)                                                   \
  __builtin_amdgcn_global_load_lds(                                                 \
      (const __attribute__((address_space(1))) unsigned int*)(gptr),                \
      (__attribute__((address_space(3))) unsigned int*)(ldsptr), 16, 0, 0)

// ---------------------------------------------------------------------------
// Kernel 1: prep — f32 -> bf16 convert, packed {sum-of-squares, id} per row.
// One wave per row (4 rows / 256-thread block). out is fully overwritten by
// the reduce kernel, so no zeroing needed.
// ---------------------------------------------------------------------------
__global__ __launch_bounds__(256) void prep_kernel(
    const float* __restrict__ samples, const float* __restrict__ input1,
    u16* __restrict__ bf, float2* __restrict__ sqid)
{
  const int row  = blockIdx.x * 4 + (threadIdx.x >> 6);
  const int lane = threadIdx.x & 63;

  const float4 v = *(const float4*)(samples + (size_t)row * kD + lane * 4);

  float tmp[4] = {v.x, v.y, v.z, v.w};
  u16 h[4];
#pragma unroll
  for (int i = 0; i < 4; ++i) {
    union { float f; unsigned u; } c;
    c.f = tmp[i];
    unsigned r = c.u + 0x7fffu + ((c.u >> 16) & 1u);
    h[i] = (u16)(r >> 16);
  }
  *(ushort4*)(bf + (size_t)row * kD + lane * 4) = make_ushort4(h[0], h[1], h[2], h[3]);

  float ss = v.x * v.x + v.y * v.y + v.z * v.z + v.w * v.w;
#pragma unroll
  for (int m = 32; m >= 1; m >>= 1) ss += __shfl_xor(ss, m);

  if (lane == 0) {
    sqid[row] = make_float2(ss, input1[row * 32 + 7]);
  }
}

// ---------------------------------------------------------------------------
// Kernel 2: triangle gram, ATOMIC-FREE deposits, slab-per-WAVE (R11 failed
// because waves sharing a deposit address raced on plain stores — atomicAdd
// had been summing the two wave-halves. Fix: unique slab slot per wave).
//
//   rowbuf[(hh*2 + wn)][i]     <- block (r,hh), wave-col wn's row partials
//   colbuf[((c-1)*2 + wm)][j]  <- tile (r,c), wave-row wm's col partials
//
// Unique writer per address; reduce kernel sums 98 slabs into out.
//
// Coverage (unchanged from R11): pair {a,b}, d=(b-a)mod64: d=1..31 by strip
// a (c=d); d=33..63 by strip b (c=64-d); d=0 diagonal once (rows only);
// d=32 by 32 xtra blocks (c=32 -> rowbuf slots 32/33, colbuf slots 62/63).
// Grid 1056 = 64 strips x 16 chunks (c=2h+t, rolled t=0..1) + 32 xtra
// (t=1 is a wmask=0 duplicate — block-uniform multiplicative mask keeps the
// compile-time trip count; no break/runtime trip: R6/R7 spill disease).
//
// Tile body = R10 verbatim: BK=64 x 4 K-steps, 4 waves 2x2,
// mfma_f32_16x16x32_bf16 4x4/wave, global_load_lds 16B staging,
// XOR-swizzled source + swizzled ds_read_b128 (rule #21, 0 conflicts
// R1-R10), setprio around MFMA, hoisted i-side sqid, id-fold epilogue.
// ---------------------------------------------------------------------------
__global__ __launch_bounds__(256, 2) void simloss_main(
    const u16* __restrict__ bf, const float2* __restrict__ sqid,
    float* __restrict__ rowbuf, float* __restrict__ colbuf)
{
  __shared__ u16 Abuf[128 * 64];  // 16 KB
  __shared__ u16 Bbuf[128 * 64];  // 16 KB

  const int tid  = threadIdx.x;
  const int lane = tid & 63;
  const int w    = tid >> 6;       // wave 0..3
  const int wm   = w >> 1;         // wave row (0..1)
  const int wn   = w & 1;          // wave col (0..1)
  const int llo  = lane & 15;
  const int lhi  = lane >> 4;

  const int  b    = blockIdx.x;
  const bool xtra = (b >= 1024);
  const int  r    = xtra ? (b - 1024) : (b & 63);   // strip 0..63 (xtra: 0..31)
  const int  hh   = xtra ? 16 : (b >> 6);           // chunk 0..16
  const int  i0   = r * 128;

  const int sr = tid >> 3;  // staging row within 32-row chunk
  const int sl = tid & 7;   // staging 16B slot within 128B row

  // i-side row data: block-constant, hoisted (R9/R10-measured healthy)
  float sqi_s[4][4], idi[4][4];
#pragma unroll
  for (int mi = 0; mi < 4; ++mi)
#pragma unroll
    for (int rr = 0; rr < 4; ++rr) {
      const float2 p = sqid[i0 + wm * 64 + mi * 16 + lhi * 4 + rr];
      sqi_s[mi][rr] = p.x * kInvD;
      idi[mi][rr]   = p.y;
    }

  float rowacc[4][4] = {};  // carried across the 2 tiles

  for (int t = 0; t < 2; ++t) {
    const int   c      = xtra ? 32 : (hh * 2 + t);       // tile distance
    const int   j0     = ((r + c) & 63) * 128;
    const float wmaskf = (xtra && t == 1) ? 0.0f : 1.0f; // masked duplicate

    f32x4 acc[4][4];
#pragma unroll
    for (int mi = 0; mi < 4; ++mi)
#pragma unroll
      for (int ni = 0; ni < 4; ++ni) acc[mi][ni] = {0.f, 0.f, 0.f, 0.f};

#pragma unroll
    for (int kt = 0; kt < 4; ++kt) {
      const int k0 = kt * 64;
      // stage A[128x64] and B[128x64] bf16 tiles: 4 calls x 16B/thread each
#pragma unroll
      for (int cc = 0; cc < 4; ++cc) {
        const int rr  = cc * 32 + sr;
        const int ksl = sl ^ (rr & 7);  // inverse-swizzled global source
        const u16* ga = bf + (size_t)(i0 + rr) * kD + k0 + ksl * 8;
        const u16* gb = bf + (size_t)(j0 + rr) * kD + k0 + ksl * 8;
        GLOAD_LDS16(ga, Abuf + rr * 64 + sl * 8);  // linear dest = tid*16B
        GLOAD_LDS16(gb, Bbuf + rr * 64 + sl * 8);
      }
      __syncthreads();

#pragma unroll
      for (int k32 = 0; k32 < 2; ++k32) {
        bf16x8 a[4], bv[4];
#pragma unroll
        for (int mi = 0; mi < 4; ++mi) {
          const int ra   = wm * 64 + mi * 16 + llo;
          const int slot = (k32 * 4 + lhi) ^ (ra & 7);  // swizzled read
          a[mi] = *(const bf16x8*)(Abuf + ra * 64 + slot * 8);
        }
#pragma unroll
        for (int ni = 0; ni < 4; ++ni) {
          const int rb   = wn * 64 + ni * 16 + llo;
          const int slot = (k32 * 4 + lhi) ^ (rb & 7);
          bv[ni] = *(const bf16x8*)(Bbuf + rb * 64 + slot * 8);
        }
        __builtin_amdgcn_s_setprio(1);
#pragma unroll
        for (int mi = 0; mi < 4; ++mi)
#pragma unroll
          for (int ni = 0; ni < 4; ++ni)
            acc[mi][ni] = __builtin_amdgcn_mfma_f32_16x16x32_bf16(
                a[mi], bv[ni], acc[mi][ni], 0, 0, 0);
        __builtin_amdgcn_s_setprio(0);
      }
      __syncthreads();
    }

    // ---- per-tile epilogue ----
    float sqjm1[4], idj[4];
#pragma unroll
    for (int ni = 0; ni < 4; ++ni) {
      const float2 p = sqid[j0 + wn * 64 + ni * 16 + llo];
      sqjm1[ni] = p.x * kInvD - 1.0f;
      idj[ni]   = p.y;
    }

    float colacc[4] = {};
#pragma unroll
    for (int mi = 0; mi < 4; ++mi)
#pragma unroll
      for (int ni = 0; ni < 4; ++ni)
#pragma unroll
        for (int rr = 0; rr < 4; ++rr) {
          // S-1 = (sq_i + sq_j)/D - 1 - (2/D)*gram ; +1 if same id
          float s1 = fmaf(acc[mi][ni][rr], -kInv2D, sqi_s[mi][rr] + sqjm1[ni]);
          s1 += (idi[mi][rr] == idj[ni]) ? 1.0f : 0.0f;
          const float tt = s1 * s1 * wmaskf;
          rowacc[mi][rr] += tt;
          colacc[ni] += tt;
        }

    // col partials -> colbuf[(c-1)*2 + wm][j] (plain store, per-wave slot).
    // Diagonal (c==0) excluded (already fully counted in row sums).
    if (c != 0 && wmaskf != 0.0f) {
#pragma unroll
      for (int ni = 0; ni < 4; ++ni) {
        float v = colacc[ni];
        v += __shfl_xor(v, 16);
        v += __shfl_xor(v, 32);
        if (lhi == 0)
          colbuf[(size_t)((c - 1) * 2 + wm) * kN + j0 + wn * 64 + ni * 16 + llo] = v;
      }
    }
  }

  // ---- block end: row partials -> rowbuf[hh*2 + wn][i] (per-wave slot) ----
#pragma unroll
  for (int mi = 0; mi < 4; ++mi)
#pragma unroll
    for (int rr = 0; rr < 4; ++rr) {
      float v = rowacc[mi][rr];
      v += __shfl_xor(v, 1);
      v += __shfl_xor(v, 2);
      v += __shfl_xor(v, 4);
      v += __shfl_xor(v, 8);
      if (llo == 0)
        rowbuf[(size_t)(hh * 2 + wn) * kN + i0 + wm * 64 + mi * 16 + lhi * 4 + rr] = v;
    }
}

// ---------------------------------------------------------------------------
// Kernel 3: reduce — out[j] = (Σ 32(+2) row slabs + Σ 62(+2) col slabs)/N.
// rowbuf slots 32/33 (xtra) defined only for j<4096; colbuf slots 62/63 only
// for j>=4096. 32 blocks x 256 threads, fully coalesced, ~3.1 MB streamed.
// ---------------------------------------------------------------------------
__global__ __launch_bounds__(256) void reduce_kernel(
    const float* __restrict__ rowbuf, const float* __restrict__ colbuf,
    float* __restrict__ out)
{
  const int j = blockIdx.x * 256 + threadIdx.x;
  float s = 0.f;
#pragma unroll
  for (int q = 0; q < 32; ++q) s += rowbuf[(size_t)q * kN + j];
  if (j < 4096)
    s += rowbuf[(size_t)32 * kN + j] + rowbuf[(size_t)33 * kN + j];
#pragma unroll
  for (int q = 0; q < 62; ++q) s += colbuf[(size_t)q * kN + j];
  if (j >= 4096)
    s += colbuf[(size_t)62 * kN + j] + colbuf[(size_t)63 * kN + j];
  out[j] = s * kInvN;
}

// ---------------------------------------------------------------------------
extern "C" void kernel_launch(void* const* d_in, const int* in_sizes, int n_in,
                              void* d_out, int out_size, void* d_ws, size_t ws_size,
                              hipStream_t stream) {
  const float* samples = (const float*)d_in[0];
  const float* input1  = (const float*)d_in[1];
  float* out = (float*)d_out;

  char* ws = (char*)d_ws;
  u16*    bf     = (u16*)ws;                                 // 4 MB bf16 samples
  float2* sqid   = (float2*)(ws + (size_t)4 * 1024 * 1024);  // 64 KB {sq, id}
  float*  rowbuf = (float*)(ws + (size_t)4 * 1024 * 1024 + 65536);  // 34 x 32 KB
  float*  colbuf = (float*)(ws + (size_t)4 * 1024 * 1024 + 65536 +
                            (size_t)34 * kN * 4);                   // 64 x 32 KB

  prep_kernel<<<kN / 4, 256, 0, stream>>>(samples, input1, bf, sqid);
  simloss_main<<<1056, 256, 0, stream>>>(bf, sqid, rowbuf, colbuf);
  reduce_kernel<<<kN / 256, 256, 0, stream>>>(rowbuf, colbuf, out);
}

// Round 13
// 46.992 us; speedup vs baseline: 1.1050x; 1.1050x over previous
//
#include <hip/hip_runtime.h>

typedef unsigned short u16;
typedef __attribute__((ext_vector_type(8))) short bf16x8;  // 8 bf16 = 4 VGPRs (MFMA A/B frag)
typedef __attribute__((ext_vector_type(4))) float f32x4;   // MFMA C/D frag

constexpr int   kN    = 8192;
constexpr int   kD    = 256;
constexpr float kInvD = 1.0f / 256.0f;
constexpr float kInv2D = 2.0f / 256.0f;   // 2/D
constexpr float kInvN = 1.0f / 8192.0f;

#define GLOAD_LDS16(gptr, ldsptr)                                                   \
  __builtin_amdgcn_global_load_lds(                                                 \
      (const __attribute__((address_space(1))) unsigned int*)(gptr),                \
      (__attribute__((address_space(3))) unsigned int*)(ldsptr), 16, 0, 0)

// ---------------------------------------------------------------------------
// Kernel 1: prep — f32 -> bf16 convert, packed {sum-of-squares, id} per row,
// zero out. One wave per row (4 rows / 256-thread block).
// ---------------------------------------------------------------------------
__global__ __launch_bounds__(256) void prep_kernel(
    const float* __restrict__ samples, const float* __restrict__ input1,
    u16* __restrict__ bf, float2* __restrict__ sqid, float* __restrict__ out)
{
  const int row  = blockIdx.x * 4 + (threadIdx.x >> 6);
  const int lane = threadIdx.x & 63;

  const float4 v = *(const float4*)(samples + (size_t)row * kD + lane * 4);

  float tmp[4] = {v.x, v.y, v.z, v.w};
  u16 h[4];
#pragma unroll
  for (int i = 0; i < 4; ++i) {
    union { float f; unsigned u; } c;
    c.f = tmp[i];
    unsigned r = c.u + 0x7fffu + ((c.u >> 16) & 1u);
    h[i] = (u16)(r >> 16);
  }
  *(ushort4*)(bf + (size_t)row * kD + lane * 4) = make_ushort4(h[0], h[1], h[2], h[3]);

  float ss = v.x * v.x + v.y * v.y + v.z * v.z + v.w * v.w;
#pragma unroll
  for (int m = 32; m >= 1; m >>= 1) ss += __shfl_xor(ss, m);

  if (lane == 0) {
    sqid[row] = make_float2(ss, input1[row * 32 + 7]);
    out[row]  = 0.0f;
  }
}

// ---------------------------------------------------------------------------
// Kernel 2: R10's proven 512-block triangle structure + A-RESIDENT LDS.
//
// Cross-round model (R1/R4/R8/R9/R12): tile cost = 2.35 CU-us (body) +
// 3.5/tiles-per-block; wall quantizes in whole 512-block generations; body
// is STAGING-bound (MfmaUtil 15-30%). R10/R12 re-staged the block-invariant
// A-strip for every tile. Fix: stage A[128][K=256] (64 KB) ONCE into a
// 4-segment resident LDS region; K-loop stages only B (16 KB/K-step, half
// the bytes per barrier window). LDS 64+16 = 80 KB dynamic -> exactly
// 2 blocks/CU. Everything else is R10 verbatim: 64 strips x 8 chunks,
// rolled trip-4 (c = 4h+t in [0,31]), hoisted i-side sqid, carried rowacc,
// per-tile col atomics (c != 0), XOR-swizzle source+read (rule #21),
// setprio around MFMA, launch_bounds(256,2), VGPR ~120 healthy.
// Coverage: distances 0..31 here; {a,a+32} pairs in simloss_d32 below;
// d >= 33 reached as (strip b, c = 64-d).
// ---------------------------------------------------------------------------
__global__ __launch_bounds__(256, 2) void simloss_main(
    const u16* __restrict__ bf, const float2* __restrict__ sqid,
    float* __restrict__ out)
{
  extern __shared__ u16 smem[];
  u16* Abuf = smem;           // [4 kt][128 row][64 col] = 64 KB, resident
  u16* Bbuf = smem + 32768;   // [128 row][64 col] = 16 KB, per K-step

  const int tid  = threadIdx.x;
  const int lane = tid & 63;
  const int w    = tid >> 6;       // wave 0..3
  const int wm   = w >> 1;         // wave row (0..1)
  const int wn   = w & 1;          // wave col (0..1)
  const int llo  = lane & 15;
  const int lhi  = lane >> 4;

  const int r  = blockIdx.x;       // strip 0..63
  const int h  = blockIdx.y;       // offset chunk 0..7
  const int i0 = r * 128;

  const int sr = tid >> 3;  // staging row within 32-row chunk
  const int sl = tid & 7;   // staging 16B slot within 128B row

  // ---- one-time A-strip staging: 16 calls, 64 KB, all 4 K-segments ----
#pragma unroll
  for (int cc = 0; cc < 16; ++cc) {
    const int kt  = cc >> 2;
    const int rr  = (cc & 3) * 32 + sr;
    const int ksl = sl ^ (rr & 7);  // inverse-swizzled global source
    const u16* ga = bf + (size_t)(i0 + rr) * kD + kt * 64 + ksl * 8;
    GLOAD_LDS16(ga, Abuf + kt * 8192 + rr * 64 + sl * 8);
  }

  // i-side row data: block-constant, hoisted (R9/R10-measured healthy)
  float sqi_s[4][4], idi[4][4];
#pragma unroll
  for (int mi = 0; mi < 4; ++mi)
#pragma unroll
    for (int rr = 0; rr < 4; ++rr) {
      const float2 p = sqid[i0 + wm * 64 + mi * 16 + lhi * 4 + rr];
      sqi_s[mi][rr] = p.x * kInvD;
      idi[mi][rr]   = p.y;
    }

  float rowacc[4][4] = {};  // carried across tiles

  for (int t = 0; t < 4; ++t) {
    const int c  = h * 4 + t;            // tile distance 0..31
    const int j0 = ((r + c) & 63) * 128;

    f32x4 acc[4][4];
#pragma unroll
    for (int mi = 0; mi < 4; ++mi)
#pragma unroll
      for (int ni = 0; ni < 4; ++ni) acc[mi][ni] = {0.f, 0.f, 0.f, 0.f};

#pragma unroll
    for (int kt = 0; kt < 4; ++kt) {
      const int k0 = kt * 64;
      // stage ONLY the B K-slab: 4 calls x 16B/thread (16 KB)
#pragma unroll
      for (int cc = 0; cc < 4; ++cc) {
        const int rr  = cc * 32 + sr;
        const int ksl = sl ^ (rr & 7);  // inverse-swizzled global source
        const u16* gb = bf + (size_t)(j0 + rr) * kD + k0 + ksl * 8;
        GLOAD_LDS16(gb, Bbuf + rr * 64 + sl * 8);  // linear dest = tid*16B
      }
      __syncthreads();  // drains A staging too on first pass

#pragma unroll
      for (int k32 = 0; k32 < 2; ++k32) {
        bf16x8 a[4], bv[4];
#pragma unroll
        for (int mi = 0; mi < 4; ++mi) {
          const int ra   = wm * 64 + mi * 16 + llo;
          const int slot = (k32 * 4 + lhi) ^ (ra & 7);  // swizzled read
          a[mi] = *(const bf16x8*)(Abuf + kt * 8192 + ra * 64 + slot * 8);
        }
#pragma unroll
        for (int ni = 0; ni < 4; ++ni) {
          const int rb   = wn * 64 + ni * 16 + llo;
          const int slot = (k32 * 4 + lhi) ^ (rb & 7);
          bv[ni] = *(const bf16x8*)(Bbuf + rb * 64 + slot * 8);
        }
        __builtin_amdgcn_s_setprio(1);
#pragma unroll
        for (int mi = 0; mi < 4; ++mi)
#pragma unroll
          for (int ni = 0; ni < 4; ++ni)
            acc[mi][ni] = __builtin_amdgcn_mfma_f32_16x16x32_bf16(
                a[mi], bv[ni], acc[mi][ni], 0, 0, 0);
        __builtin_amdgcn_s_setprio(0);
      }
      __syncthreads();
    }

    // ---- per-tile epilogue ----
    float sqjm1[4], idj[4];
#pragma unroll
    for (int ni = 0; ni < 4; ++ni) {
      const float2 p = sqid[j0 + wn * 64 + ni * 16 + llo];
      sqjm1[ni] = p.x * kInvD - 1.0f;
      idj[ni]   = p.y;
    }

    float colacc[4] = {};
#pragma unroll
    for (int mi = 0; mi < 4; ++mi)
#pragma unroll
      for (int ni = 0; ni < 4; ++ni)
#pragma unroll
        for (int rr = 0; rr < 4; ++rr) {
          // S-1 = (sq_i + sq_j)/D - 1 - (2/D)*gram ; +1 if same id
          float s1 = fmaf(acc[mi][ni][rr], -kInv2D, sqi_s[mi][rr] + sqjm1[ni]);
          s1 += (idi[mi][rr] == idj[ni]) ? 1.0f : 0.0f;
          const float tt = s1 * s1;
          rowacc[mi][rr] += tt;
          colacc[ni] += tt;
        }

    // col sums per tile (symmetry partner) — diagonal tile (c==0) excluded
    if (c != 0) {
#pragma unroll
      for (int ni = 0; ni < 4; ++ni) {
        float v = colacc[ni];
        v += __shfl_xor(v, 16);
        v += __shfl_xor(v, 32);
        if (lhi == 0)
          atomicAdd(&out[j0 + wn * 64 + ni * 16 + llo], v * kInvN);
      }
    }
  }

  // ---- block end: row sums (carried across tiles) ----
#pragma unroll
  for (int mi = 0; mi < 4; ++mi)
#pragma unroll
    for (int rr = 0; rr < 4; ++rr) {
      float v = rowacc[mi][rr];
      v += __shfl_xor(v, 1);
      v += __shfl_xor(v, 2);
      v += __shfl_xor(v, 4);
      v += __shfl_xor(v, 8);
      if (llo == 0)
        atomicAdd(&out[i0 + wm * 64 + mi * 16 + lhi * 4 + rr], v * kInvN);
    }
}

// ---------------------------------------------------------------------------
// Kernel 3: the 32 distance-32 tiles (pairs {a, a+32}) — R10 verbatim.
// 32 single-tile blocks, ~5 us solo, static 32 KB LDS.
// ---------------------------------------------------------------------------
__global__ __launch_bounds__(256, 2) void simloss_d32(
    const u16* __restrict__ bf, const float2* __restrict__ sqid,
    float* __restrict__ out)
{
  __shared__ u16 Abuf[128 * 64];
  __shared__ u16 Bbuf[128 * 64];

  const int tid  = threadIdx.x;
  const int lane = tid & 63;
  const int w    = tid >> 6;
  const int wm   = w >> 1;
  const int wn   = w & 1;
  const int llo  = lane & 15;
  const int lhi  = lane >> 4;

  const int i0 = blockIdx.x * 128;          // strips 0..31
  const int j0 = (blockIdx.x + 32) * 128;   // partner strip

  const int sr = tid >> 3;
  const int sl = tid & 7;

  f32x4 acc[4][4];
#pragma unroll
  for (int mi = 0; mi < 4; ++mi)
#pragma unroll
    for (int ni = 0; ni < 4; ++ni) acc[mi][ni] = {0.f, 0.f, 0.f, 0.f};

#pragma unroll
  for (int kt = 0; kt < 4; ++kt) {
    const int k0 = kt * 64;
#pragma unroll
    for (int cc = 0; cc < 4; ++cc) {
      const int rr  = cc * 32 + sr;
      const int ksl = sl ^ (rr & 7);
      const u16* ga = bf + (size_t)(i0 + rr) * kD + k0 + ksl * 8;
      const u16* gb = bf + (size_t)(j0 + rr) * kD + k0 + ksl * 8;
      GLOAD_LDS16(ga, Abuf + rr * 64 + sl * 8);
      GLOAD_LDS16(gb, Bbuf + rr * 64 + sl * 8);
    }
    __syncthreads();

#pragma unroll
    for (int k32 = 0; k32 < 2; ++k32) {
      bf16x8 a[4], bv[4];
#pragma unroll
      for (int mi = 0; mi < 4; ++mi) {
        const int ra   = wm * 64 + mi * 16 + llo;
        const int slot = (k32 * 4 + lhi) ^ (ra & 7);
        a[mi] = *(const bf16x8*)(Abuf + ra * 64 + slot * 8);
      }
#pragma unroll
      for (int ni = 0; ni < 4; ++ni) {
        const int rb   = wn * 64 + ni * 16 + llo;
        const int slot = (k32 * 4 + lhi) ^ (rb & 7);
        bv[ni] = *(const bf16x8*)(Bbuf + rb * 64 + slot * 8);
      }
      __builtin_amdgcn_s_setprio(1);
#pragma unroll
      for (int mi = 0; mi < 4; ++mi)
#pragma unroll
        for (int ni = 0; ni < 4; ++ni)
          acc[mi][ni] = __builtin_amdgcn_mfma_f32_16x16x32_bf16(
              a[mi], bv[ni], acc[mi][ni], 0, 0, 0);
      __builtin_amdgcn_s_setprio(0);
    }
    __syncthreads();
  }

  float sqi_s[4][4], idi[4][4];
#pragma unroll
  for (int mi = 0; mi < 4; ++mi)
#pragma unroll
    for (int rr = 0; rr < 4; ++rr) {
      const float2 p = sqid[i0 + wm * 64 + mi * 16 + lhi * 4 + rr];
      sqi_s[mi][rr] = p.x * kInvD;
      idi[mi][rr]   = p.y;
    }
  float sqjm1[4], idj[4];
#pragma unroll
  for (int ni = 0; ni < 4; ++ni) {
    const float2 p = sqid[j0 + wn * 64 + ni * 16 + llo];
    sqjm1[ni] = p.x * kInvD - 1.0f;
    idj[ni]   = p.y;
  }

  float rowacc[4][4] = {};
  float colacc[4] = {};
#pragma unroll
  for (int mi = 0; mi < 4; ++mi)
#pragma unroll
    for (int ni = 0; ni < 4; ++ni)
#pragma unroll
      for (int rr = 0; rr < 4; ++rr) {
        float s1 = fmaf(acc[mi][ni][rr], -kInv2D, sqi_s[mi][rr] + sqjm1[ni]);
        s1 += (idi[mi][rr] == idj[ni]) ? 1.0f : 0.0f;
        const float tt = s1 * s1;
        rowacc[mi][rr] += tt;
        colacc[ni] += tt;
      }

#pragma unroll
  for (int mi = 0; mi < 4; ++mi)
#pragma unroll
    for (int rr = 0; rr < 4; ++rr) {
      float v = rowacc[mi][rr];
      v += __shfl_xor(v, 1);
      v += __shfl_xor(v, 2);
      v += __shfl_xor(v, 4);
      v += __shfl_xor(v, 8);
      if (llo == 0)
        atomicAdd(&out[i0 + wm * 64 + mi * 16 + lhi * 4 + rr], v * kInvN);
    }
#pragma unroll
  for (int ni = 0; ni < 4; ++ni) {
    float v = colacc[ni];
    v += __shfl_xor(v, 16);
    v += __shfl_xor(v, 32);
    if (lhi == 0)
      atomicAdd(&out[j0 + wn * 64 + ni * 16 + llo], v * kInvN);
  }
}

// ---------------------------------------------------------------------------
extern "C" void kernel_launch(void* const* d_in, const int* in_sizes, int n_in,
                              void* d_out, int out_size, void* d_ws, size_t ws_size,
                              hipStream_t stream) {
  const float* samples = (const float*)d_in[0];
  const float* input1  = (const float*)d_in[1];
  float* out = (float*)d_out;

  char* ws = (char*)d_ws;
  u16*    bf   = (u16*)ws;                                  // 4 MB bf16 samples
  float2* sqid = (float2*)(ws + (size_t)4 * 1024 * 1024);   // 64 KB {sq, id}

  // allow 80 KB dynamic LDS for the A-resident kernel (R5 proved mechanism)
  hipFuncSetAttribute(reinterpret_cast<const void*>(&simloss_main),
                      hipFuncAttributeMaxDynamicSharedMemorySize, 81920);

  prep_kernel<<<kN / 4, 256, 0, stream>>>(samples, input1, bf, sqid, out);
  simloss_main<<<dim3(64, 8), 256, 81920, stream>>>(bf, sqid, out);
  simloss_d32<<<32, 256, 0, stream>>>(bf, sqid, out);
}

// Round 14
// 44.776 us; speedup vs baseline: 1.1597x; 1.0495x over previous
//
#include <hip/hip_runtime.h>

typedef unsigned short u16;
typedef __attribute__((ext_vector_type(8))) short bf16x8;  // 8 bf16 = 4 VGPRs (MFMA A/B frag)
typedef __attribute__((ext_vector_type(4))) float f32x4;   // MFMA C/D frag

constexpr int   kN    = 8192;
constexpr int   kD    = 256;
constexpr float kInvD = 1.0f / 256.0f;
constexpr float kInv2D = 2.0f / 256.0f;   // 2/D
constexpr float kInvN = 1.0f / 8192.0f;

#define GLOAD_LDS16(gptr, ldsptr)                                                   \
  __builtin_amdgcn_global_load_lds(                                                 \
      (const __attribute__((address_space(1))) unsigned int*)(gptr),                \
      (__attribute__((address_space(3))) unsigned int*)(ldsptr), 16, 0, 0)

// ---------------------------------------------------------------------------
// Kernel 1: prep — f32 -> bf16 convert, packed {sum-of-squares, id} per row,
// zero out. One wave per row (4 rows / 256-thread block).
// ---------------------------------------------------------------------------
__global__ __launch_bounds__(256) void prep_kernel(
    const float* __restrict__ samples, const float* __restrict__ input1,
    u16* __restrict__ bf, float2* __restrict__ sqid, float* __restrict__ out)
{
  const int row  = blockIdx.x * 4 + (threadIdx.x >> 6);
  const int lane = threadIdx.x & 63;

  const float4 v = *(const float4*)(samples + (size_t)row * kD + lane * 4);

  float tmp[4] = {v.x, v.y, v.z, v.w};
  u16 h[4];
#pragma unroll
  for (int i = 0; i < 4; ++i) {
    union { float f; unsigned u; } c;
    c.f = tmp[i];
    unsigned r = c.u + 0x7fffu + ((c.u >> 16) & 1u);
    h[i] = (u16)(r >> 16);
  }
  *(ushort4*)(bf + (size_t)row * kD + lane * 4) = make_ushort4(h[0], h[1], h[2], h[3]);

  float ss = v.x * v.x + v.y * v.y + v.z * v.z + v.w * v.w;
#pragma unroll
  for (int m = 32; m >= 1; m >>= 1) ss += __shfl_xor(ss, m);

  if (lane == 0) {
    sqid[row] = make_float2(ss, input1[row * 32 + 7]);
    out[row]  = 0.0f;
  }
}

// ---------------------------------------------------------------------------
// Kernel 2: R10's 512-block triangle structure + T3 2-phase double-buffer.
//
// R12 exonerated atomics; R13 exonerated staging VOLUME. The 2.35 CU-us/tile
// body cost is LATENCY: stage -> syncthreads (drains the just-issued loads,
// full latency exposed) -> compute. Fix (guide T3 minimum 2-phase): A and B
// double-buffered (4 x 16 KB = 64 KB, 2 blocks/CU); per K-step issue the
// NEXT slab's global_load_lds first, compute current from the other buffer,
// then ONE __syncthreads — the vmcnt drain lands after ~400cy of ds_read+
// MFMA, so load latency hides under compute. Buffer parity is compile-time
// (kt unrolled 0..3) inside the ROLLED trip-4 tile loop (codegen health:
// R6/R7/R8 lessons — rolled tile loop, carried rowacc, hoisted i-side,
// LB(256,2)). kt=3 prefetches the next tile's first slab (wrap address is
// always valid; final iteration's prefetch is harmless waste).
// Coverage (R10 verbatim): strip r, distances c = 4h+t in 0..31; d32 pairs
// in simloss_d32; d >= 33 reached as (strip b, c = 64-d).
// ---------------------------------------------------------------------------
__global__ __launch_bounds__(256, 2) void simloss_main(
    const u16* __restrict__ bf, const float2* __restrict__ sqid,
    float* __restrict__ out)
{
  __shared__ u16 Ab0[8192], Ab1[8192], Bb0[8192], Bb1[8192];  // 4 x 16 KB

  const int tid  = threadIdx.x;
  const int lane = tid & 63;
  const int w    = tid >> 6;       // wave 0..3
  const int wm   = w >> 1;         // wave row (0..1)
  const int wn   = w & 1;          // wave col (0..1)
  const int llo  = lane & 15;
  const int lhi  = lane >> 4;

  const int r  = blockIdx.x;       // strip 0..63
  const int h  = blockIdx.y;       // offset chunk 0..7
  const int i0 = r * 128;

  const int sr = tid >> 3;  // staging row within 32-row chunk
  const int sl = tid & 7;   // staging 16B slot within 128B row

  // stage one [128][64] K-slab of one operand (4 x 16B/thread, linear dest,
  // inverse-swizzled source — rule #21 pair with the swizzled ds_read below)
#define STAGE_SLAB(dst, grow0, kt)                                          \
  {                                                                         \
    _Pragma("unroll")                                                       \
    for (int cc = 0; cc < 4; ++cc) {                                        \
      const int rr  = cc * 32 + sr;                                         \
      const int ksl = sl ^ (rr & 7);                                        \
      const u16* g  = bf + (size_t)((grow0) + rr) * kD + (kt) * 64 + ksl * 8; \
      GLOAD_LDS16(g, (dst) + rr * 64 + sl * 8);                             \
    }                                                                       \
  }

  // one K=64 compute step from the given LDS slabs (16 ds_read + 32 MFMA)
#define COMPUTE_SLAB(Asrc, Bsrc)                                            \
  {                                                                         \
    _Pragma("unroll")                                                       \
    for (int k32 = 0; k32 < 2; ++k32) {                                     \
      bf16x8 a[4], bv[4];                                                   \
      _Pragma("unroll")                                                     \
      for (int mi = 0; mi < 4; ++mi) {                                      \
        const int ra   = wm * 64 + mi * 16 + llo;                           \
        const int slot = (k32 * 4 + lhi) ^ (ra & 7);                        \
        a[mi] = *(const bf16x8*)((Asrc) + ra * 64 + slot * 8);              \
      }                                                                     \
      _Pragma("unroll")                                                     \
      for (int ni = 0; ni < 4; ++ni) {                                      \
        const int rb   = wn * 64 + ni * 16 + llo;                           \
        const int slot = (k32 * 4 + lhi) ^ (rb & 7);                        \
        bv[ni] = *(const bf16x8*)((Bsrc) + rb * 64 + slot * 8);             \
      }                                                                     \
      __builtin_amdgcn_s_setprio(1);                                        \
      _Pragma("unroll")                                                     \
      for (int mi = 0; mi < 4; ++mi)                                        \
        _Pragma("unroll")                                                   \
        for (int ni = 0; ni < 4; ++ni)                                      \
          acc[mi][ni] = __builtin_amdgcn_mfma_f32_16x16x32_bf16(            \
              a[mi], bv[ni], acc[mi][ni], 0, 0, 0);                         \
      __builtin_amdgcn_s_setprio(0);                                        \
    }                                                                       \
  }

  // i-side row data: block-constant, hoisted (R9/R10-measured healthy)
  float sqi_s[4][4], idi[4][4];
#pragma unroll
  for (int mi = 0; mi < 4; ++mi)
#pragma unroll
    for (int rr = 0; rr < 4; ++rr) {
      const float2 p = sqid[i0 + wm * 64 + mi * 16 + lhi * 4 + rr];
      sqi_s[mi][rr] = p.x * kInvD;
      idi[mi][rr]   = p.y;
    }

  float rowacc[4][4] = {};  // carried across tiles

  // ---- prologue: stage (t=0, kt=0) into buf0 ----
  {
    const int j0p = ((r + h * 4) & 63) * 128;
    STAGE_SLAB(Ab0, i0, 0);
    STAGE_SLAB(Bb0, j0p, 0);
  }
  __syncthreads();

  for (int t = 0; t < 4; ++t) {
    const int c   = h * 4 + t;                 // tile distance 0..31
    const int j0  = ((r + c) & 63) * 128;
    const int j0n = ((r + c + 1) & 63) * 128;  // next tile (last: harmless)

    f32x4 acc[4][4];
#pragma unroll
    for (int mi = 0; mi < 4; ++mi)
#pragma unroll
      for (int ni = 0; ni < 4; ++ni) acc[mi][ni] = {0.f, 0.f, 0.f, 0.f};

    // kt=0: prefetch kt1 -> buf1, compute buf0
    STAGE_SLAB(Ab1, i0, 1);
    STAGE_SLAB(Bb1, j0, 1);
    COMPUTE_SLAB(Ab0, Bb0);
    __syncthreads();
    // kt=1: prefetch kt2 -> buf0, compute buf1
    STAGE_SLAB(Ab0, i0, 2);
    STAGE_SLAB(Bb0, j0, 2);
    COMPUTE_SLAB(Ab1, Bb1);
    __syncthreads();
    // kt=2: prefetch kt3 -> buf1, compute buf0
    STAGE_SLAB(Ab1, i0, 3);
    STAGE_SLAB(Bb1, j0, 3);
    COMPUTE_SLAB(Ab0, Bb0);
    __syncthreads();
    // kt=3: prefetch NEXT TILE kt0 -> buf0, compute buf1
    STAGE_SLAB(Ab0, i0, 0);
    STAGE_SLAB(Bb0, j0n, 0);
    COMPUTE_SLAB(Ab1, Bb1);
    __syncthreads();

    // ---- per-tile epilogue ----
    float sqjm1[4], idj[4];
#pragma unroll
    for (int ni = 0; ni < 4; ++ni) {
      const float2 p = sqid[j0 + wn * 64 + ni * 16 + llo];
      sqjm1[ni] = p.x * kInvD - 1.0f;
      idj[ni]   = p.y;
    }

    float colacc[4] = {};
#pragma unroll
    for (int mi = 0; mi < 4; ++mi)
#pragma unroll
      for (int ni = 0; ni < 4; ++ni)
#pragma unroll
        for (int rr = 0; rr < 4; ++rr) {
          // S-1 = (sq_i + sq_j)/D - 1 - (2/D)*gram ; +1 if same id
          float s1 = fmaf(acc[mi][ni][rr], -kInv2D, sqi_s[mi][rr] + sqjm1[ni]);
          s1 += (idi[mi][rr] == idj[ni]) ? 1.0f : 0.0f;
          const float tt = s1 * s1;
          rowacc[mi][rr] += tt;
          colacc[ni] += tt;
        }

    // col sums per tile (symmetry partner) — diagonal tile (c==0) excluded
    if (c != 0) {
#pragma unroll
      for (int ni = 0; ni < 4; ++ni) {
        float v = colacc[ni];
        v += __shfl_xor(v, 16);
        v += __shfl_xor(v, 32);
        if (lhi == 0)
          atomicAdd(&out[j0 + wn * 64 + ni * 16 + llo], v * kInvN);
      }
    }
  }

  // ---- block end: row sums (carried across tiles) ----
#pragma unroll
  for (int mi = 0; mi < 4; ++mi)
#pragma unroll
    for (int rr = 0; rr < 4; ++rr) {
      float v = rowacc[mi][rr];
      v += __shfl_xor(v, 1);
      v += __shfl_xor(v, 2);
      v += __shfl_xor(v, 4);
      v += __shfl_xor(v, 8);
      if (llo == 0)
        atomicAdd(&out[i0 + wm * 64 + mi * 16 + lhi * 4 + rr], v * kInvN);
    }
}

// ---------------------------------------------------------------------------
// Kernel 3: the 32 distance-32 tiles (pairs {a, a+32}) — R10 verbatim.
// ---------------------------------------------------------------------------
__global__ __launch_bounds__(256, 2) void simloss_d32(
    const u16* __restrict__ bf, const float2* __restrict__ sqid,
    float* __restrict__ out)
{
  __shared__ u16 Abuf[128 * 64];
  __shared__ u16 Bbuf[128 * 64];

  const int tid  = threadIdx.x;
  const int lane = tid & 63;
  const int w    = tid >> 6;
  const int wm   = w >> 1;
  const int wn   = w & 1;
  const int llo  = lane & 15;
  const int lhi  = lane >> 4;

  const int i0 = blockIdx.x * 128;          // strips 0..31
  const int j0 = (blockIdx.x + 32) * 128;   // partner strip

  const int sr = tid >> 3;
  const int sl = tid & 7;

  f32x4 acc[4][4];
#pragma unroll
  for (int mi = 0; mi < 4; ++mi)
#pragma unroll
    for (int ni = 0; ni < 4; ++ni) acc[mi][ni] = {0.f, 0.f, 0.f, 0.f};

#pragma unroll
  for (int kt = 0; kt < 4; ++kt) {
    const int k0 = kt * 64;
#pragma unroll
    for (int cc = 0; cc < 4; ++cc) {
      const int rr  = cc * 32 + sr;
      const int ksl = sl ^ (rr & 7);
      const u16* ga = bf + (size_t)(i0 + rr) * kD + k0 + ksl * 8;
      const u16* gb = bf + (size_t)(j0 + rr) * kD + k0 + ksl * 8;
      GLOAD_LDS16(ga, Abuf + rr * 64 + sl * 8);
      GLOAD_LDS16(gb, Bbuf + rr * 64 + sl * 8);
    }
    __syncthreads();

#pragma unroll
    for (int k32 = 0; k32 < 2; ++k32) {
      bf16x8 a[4], bv[4];
#pragma unroll
      for (int mi = 0; mi < 4; ++mi) {
        const int ra   = wm * 64 + mi * 16 + llo;
        const int slot = (k32 * 4 + lhi) ^ (ra & 7);
        a[mi] = *(const bf16x8*)(Abuf + ra * 64 + slot * 8);
      }
#pragma unroll
      for (int ni = 0; ni < 4; ++ni) {
        const int rb   = wn * 64 + ni * 16 + llo;
        const int slot = (k32 * 4 + lhi) ^ (rb & 7);
        bv[ni] = *(const bf16x8*)(Bbuf + rb * 64 + slot * 8);
      }
      __builtin_amdgcn_s_setprio(1);
#pragma unroll
      for (int mi = 0; mi < 4; ++mi)
#pragma unroll
        for (int ni = 0; ni < 4; ++ni)
          acc[mi][ni] = __builtin_amdgcn_mfma_f32_16x16x32_bf16(
              a[mi], bv[ni], acc[mi][ni], 0, 0, 0);
      __builtin_amdgcn_s_setprio(0);
    }
    __syncthreads();
  }

  float sqi_s[4][4], idi[4][4];
#pragma unroll
  for (int mi = 0; mi < 4; ++mi)
#pragma unroll
    for (int rr = 0; rr < 4; ++rr) {
      const float2 p = sqid[i0 + wm * 64 + mi * 16 + lhi * 4 + rr];
      sqi_s[mi][rr] = p.x * kInvD;
      idi[mi][rr]   = p.y;
    }
  float sqjm1[4], idj[4];
#pragma unroll
  for (int ni = 0; ni < 4; ++ni) {
    const float2 p = sqid[j0 + wn * 64 + ni * 16 + llo];
    sqjm1[ni] = p.x * kInvD - 1.0f;
    idj[ni]   = p.y;
  }

  float rowacc[4][4] = {};
  float colacc[4] = {};
#pragma unroll
  for (int mi = 0; mi < 4; ++mi)
#pragma unroll
    for (int ni = 0; ni < 4; ++ni)
#pragma unroll
      for (int rr = 0; rr < 4; ++rr) {
        float s1 = fmaf(acc[mi][ni][rr], -kInv2D, sqi_s[mi][rr] + sqjm1[ni]);
        s1 += (idi[mi][rr] == idj[ni]) ? 1.0f : 0.0f;
        const float tt = s1 * s1;
        rowacc[mi][rr] += tt;
        colacc[ni] += tt;
      }

#pragma unroll
  for (int mi = 0; mi < 4; ++mi)
#pragma unroll
    for (int rr = 0; rr < 4; ++rr) {
      float v = rowacc[mi][rr];
      v += __shfl_xor(v, 1);
      v += __shfl_xor(v, 2);
      v += __shfl_xor(v, 4);
      v += __shfl_xor(v, 8);
      if (llo == 0)
        atomicAdd(&out[i0 + wm * 64 + mi * 16 + lhi * 4 + rr], v * kInvN);
    }
#pragma unroll
  for (int ni = 0; ni < 4; ++ni) {
    float v = colacc[ni];
    v += __shfl_xor(v, 16);
    v += __shfl_xor(v, 32);
    if (lhi == 0)
      atomicAdd(&out[j0 + wn * 64 + ni * 16 + llo], v * kInvN);
  }
}

// ---------------------------------------------------------------------------
extern "C" void kernel_launch(void* const* d_in, const int* in_sizes, int n_in,
                              void* d_out, int out_size, void* d_ws, size_t ws_size,
                              hipStream_t stream) {
  const float* samples = (const float*)d_in[0];
  const float* input1  = (const float*)d_in[1];
  float* out = (float*)d_out;

  char* ws = (char*)d_ws;
  u16*    bf   = (u16*)ws;                                  // 4 MB bf16 samples
  float2* sqid = (float2*)(ws + (size_t)4 * 1024 * 1024);   // 64 KB {sq, id}

  prep_kernel<<<kN / 4, 256, 0, stream>>>(samples, input1, bf, sqid, out);
  simloss_main<<<dim3(64, 8), 256, 0, stream>>>(bf, sqid, out);
  simloss_d32<<<32, 256, 0, stream>>>(bf, sqid, out);
}